// Round 8
// baseline (979.574 us; speedup 1.0000x reference)
//
#include <hip/hip_runtime.h>
#include <cmath>

typedef unsigned short u16;
typedef __attribute__((ext_vector_type(8))) short short8;
typedef __attribute__((ext_vector_type(4))) float float4v;
typedef unsigned short ushort2v __attribute__((ext_vector_type(2)));

#define S_LEN 2048
#define NTOK  8192   // B*S
#define TOPK  35
#define NT512 ((size_t)NTOK*512)

__device__ __forceinline__ u16 f2b(float f){
  unsigned int x = __float_as_uint(f);
  unsigned int r = (x + 0x7fffu + ((x >> 16) & 1u)) >> 16;
  return (u16)r;
}
__device__ __forceinline__ float b2f(u16 u){
  return __uint_as_float(((unsigned int)u) << 16);
}
__device__ __forceinline__ unsigned umax2(unsigned a, unsigned b){ return a > b ? a : b; }

// bf16(f) -> monotone-increasing u16 sort key (no NaNs assumed)
__device__ __forceinline__ unsigned key_of(float f){
  unsigned u = (unsigned)f2b(f);
  unsigned m = (u & 0x8000u) ? 0xFFFFu : 0x8000u;
  return (u ^ m) & 0xFFFFu;
}
// key -> float (bf16 value)
__device__ __forceinline__ float key_to_f(unsigned key){
  unsigned m = (key & 0x8000u) ? 0x8000u : 0xFFFFu;
  return __uint_as_float(((key ^ m) & 0xFFFFu) << 16);
}
// packed 2x u16 max/min (v_pk_max_u16 / v_pk_min_u16)
__device__ __forceinline__ unsigned pkmax(unsigned a, unsigned b){
  union { unsigned u; ushort2v v; } x, y, r;
  x.u = a; y.u = b;
  r.v = __builtin_elementwise_max(x.v, y.v);
  return r.u;
}
__device__ __forceinline__ unsigned pkmin(unsigned a, unsigned b){
  union { unsigned u; ushort2v v; } x, y, r;
  x.u = a; y.u = b;
  r.v = __builtin_elementwise_min(x.v, y.v);
  return r.u;
}

// async global->LDS 16B direct copy; LDS dest pattern = wave-uniform base + lane*16
__device__ __forceinline__ void gload16(const void* g, void* l){
  __builtin_amdgcn_global_load_lds(
      (const __attribute__((address_space(1))) unsigned int*)g,
      (__attribute__((address_space(3))) unsigned int*)l, 16, 0, 0);
}

// ---------------- weight transpose + bf16 convert: Wt[n][k] = bf16(W[k][n]) ----------------
__global__ void convert_wt(const float* __restrict__ W, u16* __restrict__ Wt, int K, int N){
  __shared__ u16 t[32][33];
  int k0 = blockIdx.y*32, n0 = blockIdx.x*32;
  int tx = threadIdx.x, ty = threadIdx.y;   // 32x8
  #pragma unroll
  for (int i = ty; i < 32; i += 8)
    t[i][tx] = f2b(W[(size_t)(k0+i)*N + n0+tx]);
  __syncthreads();
  #pragma unroll
  for (int i = ty; i < 32; i += 8)
    Wt[(size_t)(n0+i)*K + k0+tx] = t[tx][i];
}

// ---------------- embedding + sinusoidal PE (writes fp32 h + bf16 h16) ----------------
__global__ void embed_kernel(const float* __restrict__ x, const float* __restrict__ w,
                             const float* __restrict__ bias, float* __restrict__ h,
                             u16* __restrict__ h16){
  int t = blockIdx.x;          // token 0..8191
  int tid = threadIdx.x;       // 0..255
  __shared__ float xs[64];
  if (tid < 64) xs[tid] = x[(size_t)t*64 + tid];
  __syncthreads();
  float acc0 = bias[tid];
  float acc1 = bias[tid + 256];
  #pragma unroll 8
  for (int k = 0; k < 64; ++k){
    float xv = xs[k];
    acc0 += xv * w[k*512 + tid];
    acc1 += xv * w[k*512 + tid + 256];
  }
  int s = t & (S_LEN - 1);
  const float neg_ln1e4_over_D = -9.210340371976184f / 512.f;
  int c0 = tid, c1 = tid + 256;
  float a0 = (float)s * expf((float)(c0 & ~1) * neg_ln1e4_over_D);
  float p0 = (c0 & 1) ? cosf(a0) : sinf(a0);
  float a1 = (float)s * expf((float)(c1 & ~1) * neg_ln1e4_over_D);
  float p1 = (c1 & 1) ? cosf(a1) : sinf(a1);
  float v0 = acc0 + p0, v1 = acc1 + p1;
  h[(size_t)t*512 + c0] = v0;  h16[(size_t)t*512 + c0] = f2b(v0);
  h[(size_t)t*512 + c1] = v1;  h16[(size_t)t*512 + c1] = f2b(v1);
}

// ---------------- bf16 MFMA GEMM: C = A[M,*lda] @ Bt[N,*ldb]^T + bias ----------------
// 128x128 tile, BK=64, 4 waves, 4x4 16x16x32 MFMA per wave. Staging via
// global_load_lds (16B), XOR-swizzled chunk permutation on the GLOBAL side
// (LDS dst stays lane-contiguous as required).
// EPI 1: relu -> bf16 C16a[M,N]
// EPI 2: fused QKV (N=1536): q/k bf16 scatter, v fp32 scatter
// EPI 3: split-K (gridDim.z=2): z=0 -> fp32 Cf + bias, z=1 -> bf16 partial C16b
template<int EPI>
__global__ __launch_bounds__(256) void gemm_mfma(
    const u16* __restrict__ A, int lda, const u16* __restrict__ Bt, int ldb,
    const float* __restrict__ bias0, const float* __restrict__ bias1,
    const float* __restrict__ bias2,
    float* __restrict__ Cf, u16* __restrict__ C16a, u16* __restrict__ C16b,
    float* __restrict__ Cv, int M, int N, int Klen){
  __shared__ __align__(16) u16 As[128*64];
  __shared__ __align__(16) u16 Bs[128*64];
  int tid = threadIdx.x;
  int w = tid >> 6, l = tid & 63, quad = l >> 4, m = l & 15;
  int m0 = blockIdx.y*128, n0 = blockIdx.x*128;
  int mh = (w >> 1)*64, nh = (w & 1)*64;
  const u16* Ap  = A  + (size_t)blockIdx.z * Klen;
  const u16* Btp = Bt + (size_t)blockIdx.z * Klen;
  float4v acc[4][4];
  #pragma unroll
  for (int i = 0; i < 4; ++i)
    #pragma unroll
    for (int j = 0; j < 4; ++j) acc[i][j] = (float4v){0.f,0.f,0.f,0.f};

  for (int kt = 0; kt < Klen; kt += 64){
    #pragma unroll
    for (int c = 0; c < 4; ++c){
      int g = c*256 + tid;
      int row = g >> 3, sc = g & 7, dc = sc ^ (row & 7);
      gload16(Ap  + (size_t)(m0+row)*lda + kt + dc*8, As + (size_t)g*8);
      gload16(Btp + (size_t)(n0+row)*ldb + kt + dc*8, Bs + (size_t)g*8);
    }
    __syncthreads();
    #pragma unroll
    for (int kk = 0; kk < 2; ++kk){
      short8 af[4], bf[4];
      #pragma unroll
      for (int i = 0; i < 4; ++i){
        int dcx = kk*4 + quad;
        int ra = mh + i*16 + m;
        af[i] = *(const short8*)(As + (size_t)(ra*8 + (dcx ^ (ra & 7)))*8);
        int rb = nh + i*16 + m;
        bf[i] = *(const short8*)(Bs + (size_t)(rb*8 + (dcx ^ (rb & 7)))*8);
      }
      #pragma unroll
      for (int i = 0; i < 4; ++i)
        #pragma unroll
        for (int j = 0; j < 4; ++j)
          acc[i][j] = __builtin_amdgcn_mfma_f32_16x16x32_bf16(af[i], bf[j], acc[i][j], 0, 0, 0);
    }
    __syncthreads();
  }

  // C/D layout: row_local = quad*4+r, col_local = m
  #pragma unroll
  for (int i = 0; i < 4; ++i){
    #pragma unroll
    for (int j = 0; j < 4; ++j){
      int col = n0 + nh + j*16 + m;
      #pragma unroll
      for (int r = 0; r < 4; ++r){
        int row = m0 + mh + i*16 + quad*4 + r;
        float v = acc[i][j][r];
        if (EPI == 1){
          C16a[(size_t)row*N + col] = f2b(fmaxf(v + bias0[col], 0.f));
        } else if (EPI == 3){
          if (blockIdx.z == 0) Cf[(size_t)row*N + col] = v + bias0[col];
          else                 C16b[(size_t)row*N + col] = f2b(v);
        } else {
          int sel = col >> 9, n5 = col & 511;
          const float* bp = (sel == 0) ? bias0 : (sel == 1) ? bias1 : bias2;
          float vv = v + bp[n5];
          int d = n5 & 63, hh = n5 >> 6;
          int b = row >> 11, s = row & 2047;
          size_t idx = (((size_t)(b*8 + hh))*2048 + s)*64 + d;
          if (sel == 0)      C16a[idx] = f2b(vv);
          else if (sel == 1) C16b[idx] = f2b(vv);
          else               Cv[idx]  = vv;
        }
      }
    }
  }
}

// ---------------- fused MFMA scores + top-35 + softmax + P@V[:35] ----------------
// 512 thr (8 waves) per (bh, 16-query tile). Scores stored as PACKED u16 sort
// keys (pair-row per 2 queries). Packed per-lane bitonic sort, then 35-round
// rank merge with alternating full (max,2nd) butterfly / cheap broadcast rounds.
__global__ __launch_bounds__(512) void attn_mfma_topk(
    const u16* __restrict__ qb16, const u16* __restrict__ kb16,
    const float* __restrict__ vb, u16* __restrict__ aob16){
  __shared__ unsigned pr[8*2048];   // 64 KB
  int tid  = threadIdx.x;
  int w    = tid >> 6, l = tid & 63;
  int quad = l >> 4,  m = l & 15;
  int bh = blockIdx.y;
  int q0 = blockIdx.x * 16;

  const u16* Qp = qb16 + ((size_t)bh*2048 + q0 + m)*64 + quad*8;
  short8 a0 = *(const short8*)Qp;
  short8 a1 = *(const short8*)(Qp + 32);

  const u16* Kbase = kb16 + (size_t)bh*2048*64;
  for (int kt = 0; kt < 16; ++kt){
    int k0 = w*256 + kt*16;
    const u16* Kp = Kbase + (size_t)(k0 + m)*64 + quad*8;
    short8 b0 = *(const short8*)Kp;
    short8 b1 = *(const short8*)(Kp + 32);
    float4v acc = {0.f, 0.f, 0.f, 0.f};
    acc = __builtin_amdgcn_mfma_f32_16x16x32_bf16(a0, b0, acc, 0, 0, 0);
    acc = __builtin_amdgcn_mfma_f32_16x16x32_bf16(a1, b1, acc, 0, 0, 0);
    // C layout: row(query)=quad*4+r, col(key)=m. Pack rows (2c,2c+1) -> pair row quad*2+c.
    #pragma unroll
    for (int c = 0; c < 2; ++c){
      unsigned lo = key_of(acc[2*c]);
      unsigned hi = key_of(acc[2*c+1]);
      pr[(quad*2 + c)*2048 + k0 + m] = lo | (hi << 16);
    }
  }
  __syncthreads();

  unsigned* row = &pr[w*2048];   // pair row w: queries 2w, 2w+1 (wave-private now)

  // ---- load 32 packed elems (contiguous b128 reads) ----
  unsigned sc[32];
  const uint4* p4 = (const uint4*)row;
  #pragma unroll
  for (int j = 0; j < 8; ++j){
    uint4 v4 = p4[j*64 + l];
    sc[j*4+0] = v4.x; sc[j*4+1] = v4.y; sc[j*4+2] = v4.z; sc[j*4+3] = v4.w;
  }

  // ---- packed bitonic sort, descending (both query lists at once) ----
  #pragma unroll
  for (int k = 2; k <= 32; k <<= 1){
    #pragma unroll
    for (int j = k >> 1; j > 0; j >>= 1){
      #pragma unroll
      for (int i = 0; i < 32; ++i){
        int ixj = i ^ j;
        if (ixj > i){
          unsigned a = sc[i], b = sc[ixj];
          unsigned hi = pkmax(a, b), lo = pkmin(a, b);
          if ((i & k) == 0){ sc[i] = hi; sc[ixj] = lo; }
          else             { sc[i] = lo; sc[ixj] = hi; }
        }
      }
    }
  }

  // writeback sorted: element i at row[i*64 + l] (2-way bank = free)
  #pragma unroll
  for (int i = 0; i < 32; ++i) row[i*64 + l] = sc[i];

  // ---- 35-round packed rank merge, full/cheap alternating ----
  unsigned headA = sc[0] & 0xFFFFu, headB = sc[0] >> 16;
  unsigned nxtA  = sc[1] & 0xFFFFu, nxtB  = sc[1] >> 16;
  int pA = 0, pB = 0;
  unsigned tvP[TOPK];
  #pragma unroll
  for (int r = 0; r < TOPK; r += 2){
    // full packed (max, second) butterfly
    unsigned m1 = headA | (headB << 16);
    unsigned m2 = 0;
    #pragma unroll
    for (int off = 32; off > 0; off >>= 1){
      unsigned o1 = __shfl_xor(m1, off, 64);
      unsigned o2 = __shfl_xor(m2, off, 64);
      unsigned lo = pkmin(m1, o1);
      m1 = pkmax(m1, o1);
      m2 = pkmax(pkmax(m2, o2), lo);
    }
    tvP[r] = m1;
    unsigned mA = m1 & 0xFFFFu, mB = m1 >> 16;
    int ownA = __ffsll(__ballot(headA == mA)) - 1;
    if (l == ownA){ headA = nxtA; ++pA; }
    int ownB = __ffsll(__ballot(headB == mB)) - 1;
    if (l == ownB){ headB = nxtB; ++pB; }
    nxtA = (pA + 1 < 32) ? (row[(pA + 1)*64 + l] & 0xFFFFu) : 0u;
    nxtB = (pB + 1 < 32) ? (row[(pB + 1)*64 + l] >> 16)     : 0u;
    if (r + 1 < TOPK){
      // cheap round: new max = max(second-with-multiplicity, popped lane's new head)
      unsigned nA = (unsigned)__shfl((int)headA, ownA, 64);
      unsigned nB = (unsigned)__shfl((int)headB, ownB, 64);
      unsigned cA = umax2(m2 & 0xFFFFu, nA);
      unsigned cB = umax2(m2 >> 16, nB);
      tvP[r + 1] = cA | (cB << 16);
      int o2A = __ffsll(__ballot(headA == cA)) - 1;
      if (l == o2A){ headA = nxtA; ++pA; }
      int o2B = __ffsll(__ballot(headB == cB)) - 1;
      if (l == o2B){ headB = nxtB; ++pB; }
      nxtA = (pA + 1 < 32) ? (row[(pA + 1)*64 + l] & 0xFFFFu) : 0u;
      nxtB = (pB + 1 < 32) ? (row[(pB + 1)*64 + l] >> 16)     : 0u;
    }
  }

  // ---- softmax + P@V[:35] for both queries (weight r pairs with V row r) ----
  const float* Vb = vb + (size_t)bh*2048*64 + l;   // lane = d
  float vreg[TOPK];
  #pragma unroll
  for (int r = 0; r < TOPK; ++r) vreg[r] = Vb[(size_t)r*64];
  int b = bh >> 3, hh = bh & 7;
  #pragma unroll
  for (int which = 0; which < 2; ++which){
    float tv[TOPK];
    #pragma unroll
    for (int r = 0; r < TOPK; ++r){
      unsigned key = which ? (tvP[r] >> 16) : (tvP[r] & 0xFFFFu);
      tv[r] = key_to_f(key) * 0.125f;
    }
    float mx = tv[0], denom = 0.f, acc = 0.f;
    #pragma unroll
    for (int r = 0; r < TOPK; ++r){
      float e = __expf(tv[r] - mx);
      denom += e;
      acc += e * vreg[r];
    }
    acc /= denom;
    int s = q0 + w*2 + which;
    aob16[(((size_t)(b*2048 + s))*8 + hh)*64 + l] = f2b(acc);
  }
}

// ---------------- h = LayerNorm(h + t + t2(bf16)) * g + b; also bf16 copy ----------------
__global__ void resid_ln_kernel(float* __restrict__ h, const float* __restrict__ t,
                                const u16* __restrict__ t2,
                                const float* __restrict__ g, const float* __restrict__ b,
                                u16* __restrict__ h16){
  int tok = blockIdx.x;
  int tid = threadIdx.x;        // 256 threads, 2 elems each
  size_t base = (size_t)tok * 512;
  float x0 = h[base + tid]       + t[base + tid]       + b2f(t2[base + tid]);
  float x1 = h[base + tid + 256] + t[base + tid + 256] + b2f(t2[base + tid + 256]);
  __shared__ float red[8];
  int wid = tid >> 6, lane = tid & 63;

  float s = x0 + x1;
  #pragma unroll
  for (int off = 32; off > 0; off >>= 1) s += __shfl_xor(s, off, 64);
  if (lane == 0) red[wid] = s;
  __syncthreads();
  float mean = (red[0] + red[1] + red[2] + red[3]) * (1.f/512.f);

  float d0 = x0 - mean, d1 = x1 - mean;
  float sq = d0*d0 + d1*d1;
  #pragma unroll
  for (int off = 32; off > 0; off >>= 1) sq += __shfl_xor(sq, off, 64);
  if (lane == 0) red[4 + wid] = sq;
  __syncthreads();
  float var = (red[4] + red[5] + red[6] + red[7]) * (1.f/512.f);
  float inv = rsqrtf(var + 1e-5f);
  float o0 = d0 * inv * g[tid]       + b[tid];
  float o1 = d1 * inv * g[tid + 256] + b[tid + 256];
  h[base + tid]         = o0;  h16[base + tid]       = f2b(o0);
  h[base + tid + 256]   = o1;  h16[base + tid + 256] = f2b(o1);
}

// ---------------- mean over sequence ----------------
__global__ void pool_kernel(const float* __restrict__ h, float* __restrict__ pooled){
  int c = blockIdx.x * 256 + threadIdx.x;   // 0..511
  int b = blockIdx.y;
  const float* p = h + (size_t)b * 2048 * 512 + c;
  float acc = 0.f;
  for (int s = 0; s < 2048; ++s) acc += p[(size_t)s * 512];
  pooled[b*512 + c] = acc * (1.f/2048.f);
}

// ---------------- tiny decoder ----------------
__global__ void decoder_kernel(const float* __restrict__ pooled,
                               const float* __restrict__ w1, const float* __restrict__ b1,
                               const float* __restrict__ w2, const float* __restrict__ b2,
                               float* __restrict__ out){
  __shared__ float ps[4][512];
  __shared__ float hid[4][256];
  int tid = threadIdx.x;
  for (int i = tid; i < 2048; i += 256) ps[i >> 9][i & 511] = pooled[i];
  __syncthreads();
  float bb = b1[tid];
  for (int b = 0; b < 4; ++b){
    float acc = bb;
    for (int k = 0; k < 512; ++k) acc += ps[b][k] * w1[k*256 + tid];
    hid[b][tid] = fmaxf(acc, 0.f);
  }
  __syncthreads();
  if (tid < 8){
    int b = tid >> 1, c = tid & 1;
    float acc = b2[c];
    for (int j = 0; j < 256; ++j) acc += hid[b][j] * w2[j*2 + c];
    out[b*2 + c] = acc;
  }
}

extern "C" void kernel_launch(void* const* d_in, const int* in_sizes, int n_in,
                              void* d_out, int out_size, void* d_ws, size_t ws_size,
                              hipStream_t stream){
  const float* x     = (const float*)d_in[0];
  const float* emb_w = (const float*)d_in[1];
  const float* emb_b = (const float*)d_in[2];
  const float* wq    = (const float*)d_in[3];
  const float* bq    = (const float*)d_in[4];
  const float* wk    = (const float*)d_in[5];
  const float* bk    = (const float*)d_in[6];
  const float* wv    = (const float*)d_in[7];
  const float* bv    = (const float*)d_in[8];
  const float* wo    = (const float*)d_in[9];
  const float* bo    = (const float*)d_in[10];
  const float* ff1w  = (const float*)d_in[11];
  const float* ff1b  = (const float*)d_in[12];
  const float* ff2w  = (const float*)d_in[13];
  const float* ff2b  = (const float*)d_in[14];
  const float* ln1g  = (const float*)d_in[15];
  const float* ln1b  = (const float*)d_in[16];
  const float* ln2g  = (const float*)d_in[17];
  const float* ln2b  = (const float*)d_in[18];
  const float* d1w   = (const float*)d_in[19];
  const float* d1b   = (const float*)d_in[20];
  const float* d2w   = (const float*)d_in[21];
  const float* d2b   = (const float*)d_in[22];

  // ---- workspace layout (~92 MB) ----
  // split-K bf16 partials reuse dead buffers: wo -> k16, ff2 -> aob16
  float* h      = (float*)d_ws;
  float* tmp    = h + NT512;
  u16*   u      = (u16*)(tmp + NT512);
  u16*   h16    = u;
  u16*   q16    = u + NT512;
  u16*   k16    = u + 2*NT512;
  float* vb     = (float*)(u + 3*NT512);
  u16*   ff16   = q16;                 // 32 MB overlay of q16+k16+vb
  u16*   aob16  = (u16*)(vb + NT512);
  u16*   wt     = aob16 + NT512;
  u16*   wt_qkv = wt;                          // 2 x 1536*512
  u16*   wt_wo  = wt_qkv + (size_t)2*1536*512; // 2 x 512*512
  u16*   wt_ff1 = wt_wo  + (size_t)2*512*512;  // 2 x 2048*512
  u16*   wt_ff2 = wt_ff1 + (size_t)2*2048*512; // 2 x 512*2048
  float* pooled = (float*)(wt_ff2 + (size_t)2*512*2048);

  dim3 tblk(32, 8);
  for (int l = 0; l < 2; ++l){
    convert_wt<<<dim3(16, 16), tblk, 0, stream>>>(wq + (size_t)l*512*512, wt_qkv + (size_t)l*1536*512,            512, 512);
    convert_wt<<<dim3(16, 16), tblk, 0, stream>>>(wk + (size_t)l*512*512, wt_qkv + (size_t)l*1536*512 + 512*512,  512, 512);
    convert_wt<<<dim3(16, 16), tblk, 0, stream>>>(wv + (size_t)l*512*512, wt_qkv + (size_t)l*1536*512 + 1024*512, 512, 512);
    convert_wt<<<dim3(16, 16), tblk, 0, stream>>>(wo + (size_t)l*512*512, wt_wo + (size_t)l*512*512, 512, 512);
    convert_wt<<<dim3(64, 16), tblk, 0, stream>>>(ff1w + (size_t)l*512*2048, wt_ff1 + (size_t)l*2048*512, 512, 2048);
    convert_wt<<<dim3(16, 64), tblk, 0, stream>>>(ff2w + (size_t)l*2048*512, wt_ff2 + (size_t)l*512*2048, 2048, 512);
  }

  embed_kernel<<<NTOK, 256, 0, stream>>>(x, emb_w, emb_b, h, h16);

  for (int l = 0; l < 2; ++l){
    // fused QKV: N=1536, scatter epilogue
    gemm_mfma<2><<<dim3(12, 64), 256, 0, stream>>>(
        h16, 512, wt_qkv + (size_t)l*1536*512, 512,
        bq + l*512, bk + l*512, bv + l*512,
        nullptr, q16, k16, vb, NTOK, 1536, 512);

    attn_mfma_topk<<<dim3(128, 32), 512, 0, stream>>>(q16, k16, vb, aob16);

    // wo: split-K x2 (Klen=256 each), partial1 bf16 -> k16 (dead after attn)
    gemm_mfma<3><<<dim3(4, 64, 2), 256, 0, stream>>>(
        aob16, 512, wt_wo + (size_t)l*512*512, 512,
        bo + l*512, nullptr, nullptr,
        tmp, nullptr, k16, nullptr, NTOK, 512, 256);
    resid_ln_kernel<<<NTOK, 256, 0, stream>>>(h, tmp, k16, ln1g + l*512, ln1b + l*512, h16);

    gemm_mfma<1><<<dim3(16, 64), 256, 0, stream>>>(
        h16, 512, wt_ff1 + (size_t)l*2048*512, 512,
        ff1b + l*2048, nullptr, nullptr,
        nullptr, ff16, nullptr, nullptr, NTOK, 2048, 512);

    // ff2: split-K x2 (Klen=1024 each, stride 2048), partial1 bf16 -> aob16 (dead)
    gemm_mfma<3><<<dim3(4, 64, 2), 256, 0, stream>>>(
        ff16, 2048, wt_ff2 + (size_t)l*512*2048, 2048,
        ff2b + l*512, nullptr, nullptr,
        tmp, nullptr, aob16, nullptr, NTOK, 512, 1024);
    resid_ln_kernel<<<NTOK, 256, 0, stream>>>(h, tmp, aob16, ln2g + l*512, ln2b + l*512, h16);
  }

  pool_kernel<<<dim3(2, 4), 256, 0, stream>>>(h, pooled);
  decoder_kernel<<<1, 256, 0, stream>>>(pooled, d1w, d1b, d2w, d2b, (float*)d_out);
}

// Round 9
// 838.075 us; speedup vs baseline: 1.1688x; 1.1688x over previous
//
#include <hip/hip_runtime.h>
#include <cmath>

typedef unsigned short u16;
typedef __attribute__((ext_vector_type(8))) short short8;
typedef __attribute__((ext_vector_type(4))) float float4v;
typedef unsigned short ushort2v __attribute__((ext_vector_type(2)));

#define S_LEN 2048
#define NTOK  8192   // B*S
#define TOPK  35
#define NT512 ((size_t)NTOK*512)

__device__ __forceinline__ u16 f2b(float f){
  unsigned int x = __float_as_uint(f);
  unsigned int r = (x + 0x7fffu + ((x >> 16) & 1u)) >> 16;
  return (u16)r;
}
__device__ __forceinline__ float b2f(u16 u){
  return __uint_as_float(((unsigned int)u) << 16);
}
__device__ __forceinline__ unsigned umax2(unsigned a, unsigned b){ return a > b ? a : b; }

// bf16(f) -> monotone-increasing u16 sort key (no NaNs assumed)
__device__ __forceinline__ unsigned key_of(float f){
  unsigned u = (unsigned)f2b(f);
  unsigned m = (u & 0x8000u) ? 0xFFFFu : 0x8000u;
  return (u ^ m) & 0xFFFFu;
}
__device__ __forceinline__ float key_to_f(unsigned key){
  unsigned m = (key & 0x8000u) ? 0x8000u : 0xFFFFu;
  return __uint_as_float(((key ^ m) & 0xFFFFu) << 16);
}
__device__ __forceinline__ unsigned pkmax(unsigned a, unsigned b){
  union { unsigned u; ushort2v v; } x, y, r;
  x.u = a; y.u = b;
  r.v = __builtin_elementwise_max(x.v, y.v);
  return r.u;
}
__device__ __forceinline__ unsigned pkmin(unsigned a, unsigned b){
  union { unsigned u; ushort2v v; } x, y, r;
  x.u = a; y.u = b;
  r.v = __builtin_elementwise_min(x.v, y.v);
  return r.u;
}

// async global->LDS 16B direct copy; LDS dest pattern = wave-uniform base + lane*16
__device__ __forceinline__ void gload16(const void* g, void* l){
  __builtin_amdgcn_global_load_lds(
      (const __attribute__((address_space(1))) unsigned int*)g,
      (__attribute__((address_space(3))) unsigned int*)l, 16, 0, 0);
}

// ---------------- fused weight transpose + bf16 convert (all 12 weights) ----------------
// 32x32 tiles; blockIdx.y = layer, blockIdx.x = flat tile id across 6 segments.
struct WtArgs {
  const float* wq; const float* wk; const float* wv; const float* wo;
  const float* ff1w; const float* ff2w;
  u16* wt_qkv; u16* wt_wo; u16* wt_ff1; u16* wt_ff2;
};
__global__ void convert_all(WtArgs a){
  __shared__ u16 t[32][33];
  int l = blockIdx.y;
  int tt = blockIdx.x;
  const float* W; u16* Wt; int K, N, tx_, ty_;
  if (tt < 1024){                 // qkv (3 segs) + wo, all 512x512, 16x16 tiles
    int seg = tt >> 8, r = tt & 255;
    tx_ = r & 15; ty_ = r >> 4; K = 512; N = 512;
    if (seg == 0){ W = a.wq + (size_t)l*262144; Wt = a.wt_qkv + (size_t)l*786432; }
    else if (seg == 1){ W = a.wk + (size_t)l*262144; Wt = a.wt_qkv + (size_t)l*786432 + 262144; }
    else if (seg == 2){ W = a.wv + (size_t)l*262144; Wt = a.wt_qkv + (size_t)l*786432 + 524288; }
    else { W = a.wo + (size_t)l*262144; Wt = a.wt_wo + (size_t)l*262144; }
  } else if (tt < 2048){          // ff1: K=512, N=2048 -> tiles 64 x 16
    int r = tt - 1024;
    tx_ = r & 63; ty_ = r >> 6; K = 512; N = 2048;
    W = a.ff1w + (size_t)l*1048576; Wt = a.wt_ff1 + (size_t)l*1048576;
  } else {                        // ff2: K=2048, N=512 -> tiles 16 x 64
    int r = tt - 2048;
    tx_ = r & 15; ty_ = r >> 4; K = 2048; N = 512;
    W = a.ff2w + (size_t)l*1048576; Wt = a.wt_ff2 + (size_t)l*1048576;
  }
  int k0 = ty_*32, n0 = tx_*32;
  int tx = threadIdx.x, ty = threadIdx.y;   // 32x8
  #pragma unroll
  for (int i = ty; i < 32; i += 8)
    t[i][tx] = f2b(W[(size_t)(k0+i)*N + n0+tx]);
  __syncthreads();
  #pragma unroll
  for (int i = ty; i < 32; i += 8)
    Wt[(size_t)(n0+i)*K + k0+tx] = t[tx][i];
}

// ---------------- embedding + sinusoidal PE (writes fp32 h + bf16 h16) ----------------
__global__ void embed_kernel(const float* __restrict__ x, const float* __restrict__ w,
                             const float* __restrict__ bias, float* __restrict__ h,
                             u16* __restrict__ h16){
  int t = blockIdx.x;          // token 0..8191
  int tid = threadIdx.x;       // 0..255
  __shared__ float xs[64];
  if (tid < 64) xs[tid] = x[(size_t)t*64 + tid];
  __syncthreads();
  float acc0 = bias[tid];
  float acc1 = bias[tid + 256];
  #pragma unroll 8
  for (int k = 0; k < 64; ++k){
    float xv = xs[k];
    acc0 += xv * w[k*512 + tid];
    acc1 += xv * w[k*512 + tid + 256];
  }
  int s = t & (S_LEN - 1);
  const float neg_ln1e4_over_D = -9.210340371976184f / 512.f;
  int c0 = tid, c1 = tid + 256;
  float a0 = (float)s * expf((float)(c0 & ~1) * neg_ln1e4_over_D);
  float p0 = (c0 & 1) ? cosf(a0) : sinf(a0);
  float a1 = (float)s * expf((float)(c1 & ~1) * neg_ln1e4_over_D);
  float p1 = (c1 & 1) ? cosf(a1) : sinf(a1);
  float v0 = acc0 + p0, v1 = acc1 + p1;
  h[(size_t)t*512 + c0] = v0;  h16[(size_t)t*512 + c0] = f2b(v0);
  h[(size_t)t*512 + c1] = v1;  h16[(size_t)t*512 + c1] = f2b(v1);
}

// ---------------- bf16 MFMA GEMM: C = A[M,lda] @ Bt[N,ldb]^T + bias ----------------
// 128x128 tile, BK=64, 4 waves, 4x4 16x16x32 MFMA per wave. global_load_lds
// staging; XOR chunk swizzle on the GLOBAL side (LDS dst lane-contiguous).
// EPI 0: fp32 Cf[M,N]; EPI 1: relu -> bf16 C16a; EPI 2: fused QKV scatter.
template<int EPI>
__global__ __launch_bounds__(256) void gemm_mfma(
    const u16* __restrict__ A, int lda, const u16* __restrict__ Bt, int ldb,
    const float* __restrict__ bias0, const float* __restrict__ bias1,
    const float* __restrict__ bias2,
    float* __restrict__ Cf, u16* __restrict__ C16a, u16* __restrict__ C16b,
    float* __restrict__ Cv, int M, int N, int Klen){
  __shared__ __align__(16) u16 As[128*64];
  __shared__ __align__(16) u16 Bs[128*64];
  int tid = threadIdx.x;
  int w = tid >> 6, l = tid & 63, quad = l >> 4, m = l & 15;
  int m0 = blockIdx.y*128, n0 = blockIdx.x*128;
  int mh = (w >> 1)*64, nh = (w & 1)*64;
  float4v acc[4][4];
  #pragma unroll
  for (int i = 0; i < 4; ++i)
    #pragma unroll
    for (int j = 0; j < 4; ++j) acc[i][j] = (float4v){0.f,0.f,0.f,0.f};

  for (int kt = 0; kt < Klen; kt += 64){
    #pragma unroll
    for (int c = 0; c < 4; ++c){
      int g = c*256 + tid;
      int row = g >> 3, sc = g & 7, dc = sc ^ (row & 7);
      gload16(A  + (size_t)(m0+row)*lda + kt + dc*8, As + (size_t)g*8);
      gload16(Bt + (size_t)(n0+row)*ldb + kt + dc*8, Bs + (size_t)g*8);
    }
    __syncthreads();
    #pragma unroll
    for (int kk = 0; kk < 2; ++kk){
      short8 af[4], bf[4];
      #pragma unroll
      for (int i = 0; i < 4; ++i){
        int dcx = kk*4 + quad;
        int ra = mh + i*16 + m;
        af[i] = *(const short8*)(As + (size_t)(ra*8 + (dcx ^ (ra & 7)))*8);
        int rb = nh + i*16 + m;
        bf[i] = *(const short8*)(Bs + (size_t)(rb*8 + (dcx ^ (rb & 7)))*8);
      }
      #pragma unroll
      for (int i = 0; i < 4; ++i)
        #pragma unroll
        for (int j = 0; j < 4; ++j)
          acc[i][j] = __builtin_amdgcn_mfma_f32_16x16x32_bf16(af[i], bf[j], acc[i][j], 0, 0, 0);
    }
    __syncthreads();
  }

  // C/D layout: row_local = quad*4+r, col_local = m
  #pragma unroll
  for (int i = 0; i < 4; ++i){
    #pragma unroll
    for (int j = 0; j < 4; ++j){
      int col = n0 + nh + j*16 + m;
      #pragma unroll
      for (int r = 0; r < 4; ++r){
        int row = m0 + mh + i*16 + quad*4 + r;
        float v = acc[i][j][r];
        if (EPI == 0){
          Cf[(size_t)row*N + col] = v + bias0[col];
        } else if (EPI == 1){
          C16a[(size_t)row*N + col] = f2b(fmaxf(v + bias0[col], 0.f));
        } else {
          int sel = col >> 9, n5 = col & 511;
          const float* bp = (sel == 0) ? bias0 : (sel == 1) ? bias1 : bias2;
          float vv = v + bp[n5];
          int d = n5 & 63, hh = n5 >> 6;
          int b = row >> 11, s = row & 2047;
          size_t idx = (((size_t)(b*8 + hh))*2048 + s)*64 + d;
          if (sel == 0)      C16a[idx] = f2b(vv);
          else if (sel == 1) C16b[idx] = f2b(vv);
          else               Cv[idx]  = vv;
        }
      }
    }
  }
}

// ---------------- fused MFMA scores + top-35 + softmax + P@V[:35] ----------------
__global__ __launch_bounds__(512) void attn_mfma_topk(
    const u16* __restrict__ qb16, const u16* __restrict__ kb16,
    const float* __restrict__ vb, u16* __restrict__ aob16){
  __shared__ unsigned pr[8*2048];   // 64 KB
  int tid  = threadIdx.x;
  int w    = tid >> 6, l = tid & 63;
  int quad = l >> 4,  m = l & 15;
  int bh = blockIdx.y;
  int q0 = blockIdx.x * 16;

  const u16* Qp = qb16 + ((size_t)bh*2048 + q0 + m)*64 + quad*8;
  short8 a0 = *(const short8*)Qp;
  short8 a1 = *(const short8*)(Qp + 32);

  const u16* Kbase = kb16 + (size_t)bh*2048*64;
  for (int kt = 0; kt < 16; ++kt){
    int k0 = w*256 + kt*16;
    const u16* Kp = Kbase + (size_t)(k0 + m)*64 + quad*8;
    short8 b0 = *(const short8*)Kp;
    short8 b1 = *(const short8*)(Kp + 32);
    float4v acc = {0.f, 0.f, 0.f, 0.f};
    acc = __builtin_amdgcn_mfma_f32_16x16x32_bf16(a0, b0, acc, 0, 0, 0);
    acc = __builtin_amdgcn_mfma_f32_16x16x32_bf16(a1, b1, acc, 0, 0, 0);
    #pragma unroll
    for (int c = 0; c < 2; ++c){
      unsigned lo = key_of(acc[2*c]);
      unsigned hi = key_of(acc[2*c+1]);
      pr[(quad*2 + c)*2048 + k0 + m] = lo | (hi << 16);
    }
  }
  __syncthreads();

  unsigned* row = &pr[w*2048];   // pair row w: queries 2w, 2w+1 (wave-private now)

  unsigned sc[32];
  const uint4* p4 = (const uint4*)row;
  #pragma unroll
  for (int j = 0; j < 8; ++j){
    uint4 v4 = p4[j*64 + l];
    sc[j*4+0] = v4.x; sc[j*4+1] = v4.y; sc[j*4+2] = v4.z; sc[j*4+3] = v4.w;
  }

  // packed bitonic sort, descending (both query lists at once)
  #pragma unroll
  for (int k = 2; k <= 32; k <<= 1){
    #pragma unroll
    for (int j = k >> 1; j > 0; j >>= 1){
      #pragma unroll
      for (int i = 0; i < 32; ++i){
        int ixj = i ^ j;
        if (ixj > i){
          unsigned a = sc[i], b = sc[ixj];
          unsigned hi = pkmax(a, b), lo = pkmin(a, b);
          if ((i & k) == 0){ sc[i] = hi; sc[ixj] = lo; }
          else             { sc[i] = lo; sc[ixj] = hi; }
        }
      }
    }
  }

  #pragma unroll
  for (int i = 0; i < 32; ++i) row[i*64 + l] = sc[i];

  // 35-round packed rank merge, full/cheap alternating
  unsigned headA = sc[0] & 0xFFFFu, headB = sc[0] >> 16;
  unsigned nxtA  = sc[1] & 0xFFFFu, nxtB  = sc[1] >> 16;
  int pA = 0, pB = 0;
  unsigned tvP[TOPK];
  #pragma unroll
  for (int r = 0; r < TOPK; r += 2){
    unsigned m1 = headA | (headB << 16);
    unsigned m2 = 0;
    #pragma unroll
    for (int off = 32; off > 0; off >>= 1){
      unsigned o1 = __shfl_xor(m1, off, 64);
      unsigned o2 = __shfl_xor(m2, off, 64);
      unsigned lo = pkmin(m1, o1);
      m1 = pkmax(m1, o1);
      m2 = pkmax(pkmax(m2, o2), lo);
    }
    tvP[r] = m1;
    unsigned mA = m1 & 0xFFFFu, mB = m1 >> 16;
    int ownA = __ffsll(__ballot(headA == mA)) - 1;
    if (l == ownA){ headA = nxtA; ++pA; }
    int ownB = __ffsll(__ballot(headB == mB)) - 1;
    if (l == ownB){ headB = nxtB; ++pB; }
    nxtA = (pA + 1 < 32) ? (row[(pA + 1)*64 + l] & 0xFFFFu) : 0u;
    nxtB = (pB + 1 < 32) ? (row[(pB + 1)*64 + l] >> 16)     : 0u;
    if (r + 1 < TOPK){
      unsigned nA = (unsigned)__shfl((int)headA, ownA, 64);
      unsigned nB = (unsigned)__shfl((int)headB, ownB, 64);
      unsigned cA = umax2(m2 & 0xFFFFu, nA);
      unsigned cB = umax2(m2 >> 16, nB);
      tvP[r + 1] = cA | (cB << 16);
      int o2A = __ffsll(__ballot(headA == cA)) - 1;
      if (l == o2A){ headA = nxtA; ++pA; }
      int o2B = __ffsll(__ballot(headB == cB)) - 1;
      if (l == o2B){ headB = nxtB; ++pB; }
      nxtA = (pA + 1 < 32) ? (row[(pA + 1)*64 + l] & 0xFFFFu) : 0u;
      nxtB = (pB + 1 < 32) ? (row[(pB + 1)*64 + l] >> 16)     : 0u;
    }
  }

  // softmax + P@V[:35] for both queries (weight r pairs with V row r)
  const float* Vb = vb + (size_t)bh*2048*64 + l;   // lane = d
  float vreg[TOPK];
  #pragma unroll
  for (int r = 0; r < TOPK; ++r) vreg[r] = Vb[(size_t)r*64];
  int b = bh >> 3, hh = bh & 7;
  #pragma unroll
  for (int which = 0; which < 2; ++which){
    float tv[TOPK];
    #pragma unroll
    for (int r = 0; r < TOPK; ++r){
      unsigned key = which ? (tvP[r] >> 16) : (tvP[r] & 0xFFFFu);
      tv[r] = key_to_f(key) * 0.125f;
    }
    float mx = tv[0], denom = 0.f, acc = 0.f;
    #pragma unroll
    for (int r = 0; r < TOPK; ++r){
      float e = __expf(tv[r] - mx);
      denom += e;
      acc += e * vreg[r];
    }
    acc /= denom;
    int s = q0 + w*2 + which;
    aob16[(((size_t)(b*2048 + s))*8 + hh)*64 + l] = f2b(acc);
  }
}

// ---------------- h = LayerNorm(h + t) * g + b, in place; also bf16 copy ----------------
__global__ void resid_ln_kernel(float* __restrict__ h, const float* __restrict__ t,
                                const float* __restrict__ g, const float* __restrict__ b,
                                u16* __restrict__ h16){
  int tok = blockIdx.x;
  int tid = threadIdx.x;        // 256 threads, 2 elems each
  size_t base = (size_t)tok * 512;
  float x0 = h[base + tid]       + t[base + tid];
  float x1 = h[base + tid + 256] + t[base + tid + 256];
  __shared__ float red[8];
  int wid = tid >> 6, lane = tid & 63;

  float s = x0 + x1;
  #pragma unroll
  for (int off = 32; off > 0; off >>= 1) s += __shfl_xor(s, off, 64);
  if (lane == 0) red[wid] = s;
  __syncthreads();
  float mean = (red[0] + red[1] + red[2] + red[3]) * (1.f/512.f);

  float d0 = x0 - mean, d1 = x1 - mean;
  float sq = d0*d0 + d1*d1;
  #pragma unroll
  for (int off = 32; off > 0; off >>= 1) sq += __shfl_xor(sq, off, 64);
  if (lane == 0) red[4 + wid] = sq;
  __syncthreads();
  float var = (red[4] + red[5] + red[6] + red[7]) * (1.f/512.f);
  float inv = rsqrtf(var + 1e-5f);
  float o0 = d0 * inv * g[tid]       + b[tid];
  float o1 = d1 * inv * g[tid + 256] + b[tid + 256];
  h[base + tid]         = o0;  h16[base + tid]       = f2b(o0);
  h[base + tid + 256]   = o1;  h16[base + tid + 256] = f2b(o1);
}

// ---------------- mean over sequence: parallel partial sums + atomicAdd ----------------
__global__ void pool_zero(float* __restrict__ pooled){
  pooled[blockIdx.x*512 + threadIdx.x] = 0.f;   // grid 4, block 512
}
__global__ void pool_kernel(const float* __restrict__ h, float* __restrict__ pooled){
  int c = blockIdx.x * 256 + threadIdx.x;   // 0..511
  int b = blockIdx.y;
  int s0 = blockIdx.z * 64;
  const float* p = h + ((size_t)b * 2048 + s0) * 512 + c;
  float acc = 0.f;
  #pragma unroll 8
  for (int s = 0; s < 64; ++s) acc += p[(size_t)s * 512];
  atomicAdd(&pooled[b*512 + c], acc * (1.f/2048.f));
}

// ---------------- tiny decoder ----------------
__global__ void decoder_kernel(const float* __restrict__ pooled,
                               const float* __restrict__ w1, const float* __restrict__ b1,
                               const float* __restrict__ w2, const float* __restrict__ b2,
                               float* __restrict__ out){
  __shared__ float ps[4][512];
  __shared__ float hid[4][256];
  int tid = threadIdx.x;
  for (int i = tid; i < 2048; i += 256) ps[i >> 9][i & 511] = pooled[i];
  __syncthreads();
  float bb = b1[tid];
  for (int b = 0; b < 4; ++b){
    float acc = bb;
    for (int k = 0; k < 512; ++k) acc += ps[b][k] * w1[k*256 + tid];
    hid[b][tid] = fmaxf(acc, 0.f);
  }
  __syncthreads();
  if (tid < 8){
    int b = tid >> 1, c = tid & 1;
    float acc = b2[c];
    for (int j = 0; j < 256; ++j) acc += hid[b][j] * w2[j*2 + c];
    out[b*2 + c] = acc;
  }
}

extern "C" void kernel_launch(void* const* d_in, const int* in_sizes, int n_in,
                              void* d_out, int out_size, void* d_ws, size_t ws_size,
                              hipStream_t stream){
  const float* x     = (const float*)d_in[0];
  const float* emb_w = (const float*)d_in[1];
  const float* emb_b = (const float*)d_in[2];
  const float* wq    = (const float*)d_in[3];
  const float* bq    = (const float*)d_in[4];
  const float* wk    = (const float*)d_in[5];
  const float* bk    = (const float*)d_in[6];
  const float* wv    = (const float*)d_in[7];
  const float* bv    = (const float*)d_in[8];
  const float* wo    = (const float*)d_in[9];
  const float* bo    = (const float*)d_in[10];
  const float* ff1w  = (const float*)d_in[11];
  const float* ff1b  = (const float*)d_in[12];
  const float* ff2w  = (const float*)d_in[13];
  const float* ff2b  = (const float*)d_in[14];
  const float* ln1g  = (const float*)d_in[15];
  const float* ln1b  = (const float*)d_in[16];
  const float* ln2g  = (const float*)d_in[17];
  const float* ln2b  = (const float*)d_in[18];
  const float* d1w   = (const float*)d_in[19];
  const float* d1b   = (const float*)d_in[20];
  const float* d2w   = (const float*)d_in[21];
  const float* d2b   = (const float*)d_in[22];

  // ---- workspace layout (~92 MB) ----
  float* h      = (float*)d_ws;
  float* tmp    = h + NT512;
  u16*   u      = (u16*)(tmp + NT512);
  u16*   h16    = u;
  u16*   q16    = u + NT512;
  u16*   k16    = u + 2*NT512;
  float* vb     = (float*)(u + 3*NT512);
  u16*   ff16   = q16;                 // 32 MB overlay of q16+k16+vb
  u16*   aob16  = (u16*)(vb + NT512);
  u16*   wt     = aob16 + NT512;
  u16*   wt_qkv = wt;                          // 2 x 1536*512
  u16*   wt_wo  = wt_qkv + (size_t)2*1536*512; // 2 x 512*512
  u16*   wt_ff1 = wt_wo  + (size_t)2*512*512;  // 2 x 2048*512
  u16*   wt_ff2 = wt_ff1 + (size_t)2*2048*512; // 2 x 512*2048
  float* pooled = (float*)(wt_ff2 + (size_t)2*512*2048);

  WtArgs wa{wq, wk, wv, wo, ff1w, ff2w, wt_qkv, wt_wo, wt_ff1, wt_ff2};
  convert_all<<<dim3(3072, 2), dim3(32, 8), 0, stream>>>(wa);

  embed_kernel<<<NTOK, 256, 0, stream>>>(x, emb_w, emb_b, h, h16);

  for (int l = 0; l < 2; ++l){
    // fused QKV: N=1536, scatter epilogue
    gemm_mfma<2><<<dim3(12, 64), 256, 0, stream>>>(
        h16, 512, wt_qkv + (size_t)l*1536*512, 512,
        bq + l*512, bk + l*512, bv + l*512,
        nullptr, q16, k16, vb, NTOK, 1536, 512);

    attn_mfma_topk<<<dim3(128, 32), 512, 0, stream>>>(q16, k16, vb, aob16);

    gemm_mfma<0><<<dim3(4, 64), 256, 0, stream>>>(
        aob16, 512, wt_wo + (size_t)l*512*512, 512,
        bo + l*512, nullptr, nullptr,
        tmp, nullptr, nullptr, nullptr, NTOK, 512, 512);
    resid_ln_kernel<<<NTOK, 256, 0, stream>>>(h, tmp, ln1g + l*512, ln1b + l*512, h16);

    gemm_mfma<1><<<dim3(16, 64), 256, 0, stream>>>(
        h16, 512, wt_ff1 + (size_t)l*2048*512, 512,
        ff1b + l*2048, nullptr, nullptr,
        nullptr, ff16, nullptr, nullptr, NTOK, 2048, 512);

    gemm_mfma<0><<<dim3(4, 64), 256, 0, stream>>>(
        ff16, 2048, wt_ff2 + (size_t)l*512*2048, 2048,
        ff2b + l*512, nullptr, nullptr,
        tmp, nullptr, nullptr, nullptr, NTOK, 512, 2048);
    resid_ln_kernel<<<NTOK, 256, 0, stream>>>(h, tmp, ln2g + l*512, ln2b + l*512, h16);
  }

  pool_zero<<<4, 512, 0, stream>>>(pooled);
  pool_kernel<<<dim3(2, 4, 32), 256, 0, stream>>>(h, pooled);
  decoder_kernel<<<1, 256, 0, stream>>>(pooled, d1w, d1b, d2w, d2b, (float*)d_out);
}